// Round 1
// baseline (268.576 us; speedup 1.0000x reference)
//
#include <hip/hip_runtime.h>
#include <hip/hip_bf16.h>

// ---------------------------------------------------------------------------
// Self-attention MH: B=2, QL=KL=2048, D=1024, H=16, E=64.
// Pipeline: f32->bf16 converts -> 3 proj GEMMs (bf16) -> flash attn -> out GEMM.
// ---------------------------------------------------------------------------

typedef __bf16 bf16x8 __attribute__((ext_vector_type(8)));
typedef float f32x4 __attribute__((ext_vector_type(4)));
typedef unsigned short u16;

#define GLOBAL_AS __attribute__((address_space(1)))
#define LDS_AS __attribute__((address_space(3)))

static __device__ __forceinline__ u16 f2bf(float f) {
    __hip_bfloat16 h = __float2bfloat16(f);
    return __builtin_bit_cast(u16, h);
}

// ------------------------------ f32 -> bf16 --------------------------------
__global__ void cvt_bf16(const float* __restrict__ src, u16* __restrict__ dst, int n4) {
    int i = blockIdx.x * blockDim.x + threadIdx.x;
    if (i < n4) {
        float4 v = reinterpret_cast<const float4*>(src)[i];
        ushort4 o;
        o.x = f2bf(v.x); o.y = f2bf(v.y); o.z = f2bf(v.z); o.w = f2bf(v.w);
        reinterpret_cast<ushort4*>(dst)[i] = o;
    }
}

// ------------------------------ GEMM: C = A * B^T + bias -------------------
// A [M,K] row-major bf16, Bw [N,K] row-major bf16, bias[N] f32.
// 128x128 tile, BK=32, 4 waves (2x2), each wave 64x64 (4x4 frags of 16x16x32).
template<int OUT_F32>
__global__ __launch_bounds__(256, 2)
void gemm_bt(const u16* __restrict__ A, const u16* __restrict__ Bw,
             const float* __restrict__ bias, void* __restrict__ Cout,
             int M, int N, int K) {
    __shared__ __attribute__((aligned(16))) u16 aS[128 * 32];
    __shared__ __attribute__((aligned(16))) u16 bS[128 * 32];
    const int tid = threadIdx.x, wave = tid >> 6, lane = tid & 63;
    const int m0 = blockIdx.y * 128, n0 = blockIdx.x * 128;
    const int wr = wave >> 1, wc = wave & 1;
    const int lrow = lane >> 2, lcol = (lane & 3) * 8;   // staging row/col in tile
    const int fr = lane & 15, fq = lane >> 4;            // fragment coords

    f32x4 acc[4][4] = {};

    for (int k0 = 0; k0 < K; k0 += 32) {
        #pragma unroll
        for (int i = 0; i < 2; ++i) {
            int chunk = wave * 2 + i;            // 0..7, 16 rows each
            int row = chunk * 16 + lrow;
            const u16* ga = A + (size_t)(m0 + row) * K + k0 + lcol;
            const u16* gb = Bw + (size_t)(n0 + row) * K + k0 + lcol;
            __builtin_amdgcn_global_load_lds((GLOBAL_AS void*)ga,
                                             (LDS_AS void*)(aS + chunk * 512), 16, 0, 0);
            __builtin_amdgcn_global_load_lds((GLOBAL_AS void*)gb,
                                             (LDS_AS void*)(bS + chunk * 512), 16, 0, 0);
        }
        __syncthreads();
        bf16x8 af[4], bfr[4];
        #pragma unroll
        for (int m = 0; m < 4; ++m)
            af[m] = *reinterpret_cast<const bf16x8*>(&aS[(wr * 64 + m * 16 + fr) * 32 + fq * 8]);
        #pragma unroll
        for (int n = 0; n < 4; ++n)
            bfr[n] = *reinterpret_cast<const bf16x8*>(&bS[(wc * 64 + n * 16 + fr) * 32 + fq * 8]);
        #pragma unroll
        for (int m = 0; m < 4; ++m)
            #pragma unroll
            for (int n = 0; n < 4; ++n)
                acc[m][n] = __builtin_amdgcn_mfma_f32_16x16x32_bf16(af[m], bfr[n], acc[m][n], 0, 0, 0);
        __syncthreads();
    }

    // epilogue: C/D layout col=lane&15, row=(lane>>4)*4+j  [verified m89/m91]
    #pragma unroll
    for (int n = 0; n < 4; ++n) {
        int col = n0 + wc * 64 + n * 16 + fr;
        float bv = bias[col];
        #pragma unroll
        for (int m = 0; m < 4; ++m) {
            #pragma unroll
            for (int j = 0; j < 4; ++j) {
                int row = m0 + wr * 64 + m * 16 + fq * 4 + j;
                float v = acc[m][n][j] + bv;
                if (OUT_F32)
                    reinterpret_cast<float*>(Cout)[(size_t)row * N + col] = v;
                else
                    reinterpret_cast<u16*>(Cout)[(size_t)row * N + col] = f2bf(v);
            }
        }
    }
}

// ------------------------------ flash attention ----------------------------
// Grid: (QL/64, B*H). Block: 256 thr = 4 waves; wave w owns q rows [q0+16w, +16).
// K tile 64x64 staged linear [k][e]; V staged transposed [e][k]; P via per-wave LDS.
// scale = 1/sqrt(D)=1/32 (reference scales by d_model). Causal + key padding.
__global__ __launch_bounds__(256, 2)
void attn_fwd(const u16* __restrict__ Qb, const u16* __restrict__ Kb,
              const u16* __restrict__ Vb, const int* __restrict__ kpm,
              u16* __restrict__ Ob) {
    __shared__ __attribute__((aligned(16))) u16 Ks[64 * 64];
    __shared__ __attribute__((aligned(16))) u16 Vts[64 * 64];
    __shared__ __attribute__((aligned(16))) u16 Ps[4][16 * 64];
    const int tid = threadIdx.x, wave = tid >> 6, lane = tid & 63;
    const int qt = blockIdx.x, bh = blockIdx.y;
    const int b = bh >> 4, h = bh & 15;
    const int q0 = qt * 64;
    const int fr = lane & 15, fq = lane >> 4;
    const int qrow = q0 + wave * 16;

    // Q fragments held in registers (A-frag: row=lane%16, k=(lane/16)*8+j)
    const size_t qoff = (size_t)(b * 2048 + qrow + fr) * 1024 + h * 64 + fq * 8;
    bf16x8 qa0 = *reinterpret_cast<const bf16x8*>(Qb + qoff);
    bf16x8 qa1 = *reinterpret_cast<const bf16x8*>(Qb + qoff + 32);

    float m_s[4], l_s[4];
    f32x4 o_acc[4] = {};
    #pragma unroll
    for (int j = 0; j < 4; ++j) { m_s[j] = -1e30f; l_s[j] = 0.f; }

    const int vk = tid & 63, veg = tid >> 6;  // V^T staging coords

    for (int kt = 0; kt <= qt; ++kt) {
        const int k0 = kt * 64;
        if (kpm[b * 2048 + k0] != 0) break;   // monotone padding: rest all masked
        __syncthreads();                       // previous tile's LDS reads done
        // stage K [64 k][64 e] linear, via global_load_lds (1KB per chunk)
        #pragma unroll
        for (int i = 0; i < 2; ++i) {
            int chunk = wave * 2 + i;          // 0..7, 8 k-rows each
            int krow = chunk * 8 + (lane >> 3);
            const u16* gk = Kb + (size_t)(b * 2048 + k0 + krow) * 1024 + h * 64 + (lane & 7) * 8;
            __builtin_amdgcn_global_load_lds((GLOBAL_AS void*)gk,
                                             (LDS_AS void*)(Ks + chunk * 512), 16, 0, 0);
        }
        // stage V transposed [e][k] through registers
        #pragma unroll
        for (int i = 0; i < 2; ++i) {
            int e8 = veg + i * 4;              // 0..7 (blocks of 8 e's)
            ushort4 lo = reinterpret_cast<const ushort4*>(
                Vb + (size_t)(b * 2048 + k0 + vk) * 1024 + h * 64 + e8 * 8)[0];
            ushort4 hi = reinterpret_cast<const ushort4*>(
                Vb + (size_t)(b * 2048 + k0 + vk) * 1024 + h * 64 + e8 * 8 + 4)[0];
            Vts[(e8 * 8 + 0) * 64 + vk] = lo.x;
            Vts[(e8 * 8 + 1) * 64 + vk] = lo.y;
            Vts[(e8 * 8 + 2) * 64 + vk] = lo.z;
            Vts[(e8 * 8 + 3) * 64 + vk] = lo.w;
            Vts[(e8 * 8 + 4) * 64 + vk] = hi.x;
            Vts[(e8 * 8 + 5) * 64 + vk] = hi.y;
            Vts[(e8 * 8 + 6) * 64 + vk] = hi.z;
            Vts[(e8 * 8 + 7) * 64 + vk] = hi.w;
        }
        __syncthreads();

        // S = Q K^T   (B-frag: k=(lane/16)*8+j over e, col=lane&15 over k-tile)
        f32x4 s[4] = {};
        #pragma unroll
        for (int n = 0; n < 4; ++n) {
            bf16x8 kb0 = *reinterpret_cast<const bf16x8*>(&Ks[(n * 16 + fr) * 64 + fq * 8]);
            bf16x8 kb1 = *reinterpret_cast<const bf16x8*>(&Ks[(n * 16 + fr) * 64 + 32 + fq * 8]);
            s[n] = __builtin_amdgcn_mfma_f32_16x16x32_bf16(qa0, kb0, s[n], 0, 0, 0);
            s[n] = __builtin_amdgcn_mfma_f32_16x16x32_bf16(qa1, kb1, s[n], 0, 0, 0);
        }

        // scale + causal/padding mask
        float tmax[4] = {-1e30f, -1e30f, -1e30f, -1e30f};
        #pragma unroll
        for (int n = 0; n < 4; ++n) {
            int kg = k0 + n * 16 + fr;
            bool kv = (kpm[b * 2048 + kg] == 0);
            #pragma unroll
            for (int j = 0; j < 4; ++j) {
                int qg = qrow + fq * 4 + j;
                float sc = s[n][j] * 0.03125f;
                sc = (kv && kg <= qg) ? sc : -1e30f;
                s[n][j] = sc;
                tmax[j] = fmaxf(tmax[j], sc);
            }
        }
        // row max across the 16 lanes of each row-group
        #pragma unroll
        for (int off = 1; off < 16; off <<= 1)
            #pragma unroll
            for (int j = 0; j < 4; ++j)
                tmax[j] = fmaxf(tmax[j], __shfl_xor(tmax[j], off));
        float rs[4];
        #pragma unroll
        for (int j = 0; j < 4; ++j) {
            float mn = fmaxf(m_s[j], tmax[j]);
            float f = __expf(m_s[j] - mn);
            m_s[j] = mn; l_s[j] *= f; rs[j] = 0.f;
            #pragma unroll
            for (int n = 0; n < 4; ++n) o_acc[n][j] *= f;
        }
        #pragma unroll
        for (int n = 0; n < 4; ++n)
            #pragma unroll
            for (int j = 0; j < 4; ++j) {
                float p = __expf(s[n][j] - m_s[j]);
                s[n][j] = p; rs[j] += p;
            }
        #pragma unroll
        for (int off = 1; off < 16; off <<= 1)
            #pragma unroll
            for (int j = 0; j < 4; ++j)
                rs[j] += __shfl_xor(rs[j], off);
        #pragma unroll
        for (int j = 0; j < 4; ++j) l_s[j] += rs[j];

        // P (bf16) -> per-wave LDS [q 16][k 64]
        #pragma unroll
        for (int n = 0; n < 4; ++n)
            #pragma unroll
            for (int j = 0; j < 4; ++j)
                Ps[wave][(fq * 4 + j) * 64 + n * 16 + fr] = f2bf(s[n][j]);
        asm volatile("s_waitcnt lgkmcnt(0)" ::: "memory");

        // O += P V   (A-frag from Ps, B-frag from Vts rows = contiguous k)
        #pragma unroll
        for (int ks = 0; ks < 2; ++ks) {
            bf16x8 pa = *reinterpret_cast<const bf16x8*>(&Ps[wave][fr * 64 + ks * 32 + fq * 8]);
            #pragma unroll
            for (int n = 0; n < 4; ++n) {
                bf16x8 vb2 = *reinterpret_cast<const bf16x8*>(&Vts[(n * 16 + fr) * 64 + ks * 32 + fq * 8]);
                o_acc[n] = __builtin_amdgcn_mfma_f32_16x16x32_bf16(pa, vb2, o_acc[n], 0, 0, 0);
            }
        }
    }

    // epilogue: O / l  -> agg [B*L, D] bf16
    #pragma unroll
    for (int j = 0; j < 4; ++j) {
        float inv = 1.f / l_s[j];
        int row = qrow + fq * 4 + j;
        #pragma unroll
        for (int n = 0; n < 4; ++n) {
            int col = h * 64 + n * 16 + fr;
            Ob[(size_t)(b * 2048 + row) * 1024 + col] = f2bf(o_acc[n][j] * inv);
        }
    }
}

// ------------------------------ launch -------------------------------------
extern "C" void kernel_launch(void* const* d_in, const int* in_sizes, int n_in,
                              void* d_out, int out_size, void* d_ws, size_t ws_size,
                              hipStream_t stream) {
    const float* xq_f = (const float*)d_in[0];
    const float* xk_f = (const float*)d_in[1];
    // d_in[2] = dependency_mask (causal, reimplemented analytically)
    const int* kpm = (const int*)d_in[3];
    const float* Wq = (const float*)d_in[4];
    const float* bq = (const float*)d_in[5];
    const float* Wk = (const float*)d_in[6];
    const float* bk = (const float*)d_in[7];
    const float* Wv = (const float*)d_in[8];
    const float* bv = (const float*)d_in[9];
    const float* Wo = (const float*)d_in[10];
    const float* bo = (const float*)d_in[11];

    u16* ws = (u16*)d_ws;
    u16* xq = ws;                  // 4096x1024
    u16* xk = xq + 4194304;        // 4096x1024
    u16* wq = xk + 4194304;        // 1024x1024
    u16* wk = wq + 1048576;
    u16* wv = wk + 1048576;
    u16* wo = wv + 1048576;
    u16* qb = wo + 1048576;        // 4096x1024
    u16* kb2 = qb + 4194304;
    u16* vb2 = kb2 + 4194304;
    u16* ag = vb2 + 4194304;       // total ~50.3 MB

    cvt_bf16<<<4096, 256, 0, stream>>>(xq_f, xq, 1048576);
    cvt_bf16<<<4096, 256, 0, stream>>>(xk_f, xk, 1048576);
    cvt_bf16<<<1024, 256, 0, stream>>>(Wq, wq, 262144);
    cvt_bf16<<<1024, 256, 0, stream>>>(Wk, wk, 262144);
    cvt_bf16<<<1024, 256, 0, stream>>>(Wv, wv, 262144);
    cvt_bf16<<<1024, 256, 0, stream>>>(Wo, wo, 262144);

    dim3 gg(8, 32);  // N/128, M/128
    gemm_bt<0><<<gg, 256, 0, stream>>>(xq, wq, bq, qb, 4096, 1024, 1024);
    gemm_bt<0><<<gg, 256, 0, stream>>>(xk, wk, bk, kb2, 4096, 1024, 1024);
    gemm_bt<0><<<gg, 256, 0, stream>>>(xk, wv, bv, vb2, 4096, 1024, 1024);

    attn_fwd<<<dim3(32, 32), 256, 0, stream>>>(qb, kb2, vb2, kpm, ag);

    gemm_bt<1><<<gg, 256, 0, stream>>>(ag, wo, bo, (float*)d_out, 4096, 1024, 1024);
}

// Round 2
// 234.443 us; speedup vs baseline: 1.1456x; 1.1456x over previous
//
#include <hip/hip_runtime.h>
#include <hip/hip_bf16.h>

// ---------------------------------------------------------------------------
// Self-attention MH: B=2, QL=KL=2048, D=1024, H=16, E=64.
// Pipeline: f32->bf16 converts -> 3 proj GEMMs (bf16) -> flash attn -> out GEMM.
// R2: XOR-swizzled attn LDS (K/V/P), lens precompute, reversed qt, setprio.
// ---------------------------------------------------------------------------

typedef __bf16 bf16x8 __attribute__((ext_vector_type(8)));
typedef float f32x4 __attribute__((ext_vector_type(4)));
typedef unsigned short u16;

#define GLOBAL_AS __attribute__((address_space(1)))
#define LDS_AS __attribute__((address_space(3)))

static __device__ __forceinline__ u16 f2bf(float f) {
    __hip_bfloat16 h = __float2bfloat16(f);
    return __builtin_bit_cast(u16, h);
}

// ------------------------------ f32 -> bf16 --------------------------------
__global__ void cvt_bf16(const float* __restrict__ src, u16* __restrict__ dst, int n4) {
    int i = blockIdx.x * blockDim.x + threadIdx.x;
    if (i < n4) {
        float4 v = reinterpret_cast<const float4*>(src)[i];
        ushort4 o;
        o.x = f2bf(v.x); o.y = f2bf(v.y); o.z = f2bf(v.z); o.w = f2bf(v.w);
        reinterpret_cast<ushort4*>(dst)[i] = o;
    }
}

// ---------------------- padding lengths (monotone mask) --------------------
__global__ void compute_lens(const int* __restrict__ kpm, int* __restrict__ lens) {
    const int b = blockIdx.x, tid = threadIdx.x;   // 1024 threads
    int cnt = 0;
    for (int i = tid; i < 2048; i += 1024) cnt += (kpm[b * 2048 + i] == 0) ? 1 : 0;
    #pragma unroll
    for (int off = 32; off; off >>= 1) cnt += __shfl_down(cnt, off);
    __shared__ int wsum[16];
    if ((tid & 63) == 0) wsum[tid >> 6] = cnt;
    __syncthreads();
    if (tid == 0) {
        int t = 0;
        #pragma unroll
        for (int w = 0; w < 16; ++w) t += wsum[w];
        lens[b] = t;
    }
}

// ------------------------------ GEMM: C = A * B^T + bias -------------------
// A [M,K] row-major bf16, Bw [N,K] row-major bf16, bias[N] f32.
// 128x128 tile, BK=32, 4 waves (2x2), each wave 64x64 (4x4 frags of 16x16x32).
template<int OUT_F32>
__global__ __launch_bounds__(256, 2)
void gemm_bt(const u16* __restrict__ A, const u16* __restrict__ Bw,
             const float* __restrict__ bias, void* __restrict__ Cout,
             int M, int N, int K) {
    __shared__ __attribute__((aligned(16))) u16 aS[128 * 32];
    __shared__ __attribute__((aligned(16))) u16 bS[128 * 32];
    const int tid = threadIdx.x, wave = tid >> 6, lane = tid & 63;
    const int m0 = blockIdx.y * 128, n0 = blockIdx.x * 128;
    const int wr = wave >> 1, wc = wave & 1;
    const int lrow = lane >> 2, lcol = (lane & 3) * 8;   // staging row/col in tile
    const int fr = lane & 15, fq = lane >> 4;            // fragment coords

    f32x4 acc[4][4] = {};

    for (int k0 = 0; k0 < K; k0 += 32) {
        #pragma unroll
        for (int i = 0; i < 2; ++i) {
            int chunk = wave * 2 + i;            // 0..7, 16 rows each
            int row = chunk * 16 + lrow;
            const u16* ga = A + (size_t)(m0 + row) * K + k0 + lcol;
            const u16* gb = Bw + (size_t)(n0 + row) * K + k0 + lcol;
            __builtin_amdgcn_global_load_lds((GLOBAL_AS void*)ga,
                                             (LDS_AS void*)(aS + chunk * 512), 16, 0, 0);
            __builtin_amdgcn_global_load_lds((GLOBAL_AS void*)gb,
                                             (LDS_AS void*)(bS + chunk * 512), 16, 0, 0);
        }
        __syncthreads();
        bf16x8 af[4], bfr[4];
        #pragma unroll
        for (int m = 0; m < 4; ++m)
            af[m] = *reinterpret_cast<const bf16x8*>(&aS[(wr * 64 + m * 16 + fr) * 32 + fq * 8]);
        #pragma unroll
        for (int n = 0; n < 4; ++n)
            bfr[n] = *reinterpret_cast<const bf16x8*>(&bS[(wc * 64 + n * 16 + fr) * 32 + fq * 8]);
        #pragma unroll
        for (int m = 0; m < 4; ++m)
            #pragma unroll
            for (int n = 0; n < 4; ++n)
                acc[m][n] = __builtin_amdgcn_mfma_f32_16x16x32_bf16(af[m], bfr[n], acc[m][n], 0, 0, 0);
        __syncthreads();
    }

    // epilogue: C/D layout col=lane&15, row=(lane>>4)*4+j  [verified m89/m91]
    #pragma unroll
    for (int n = 0; n < 4; ++n) {
        int col = n0 + wc * 64 + n * 16 + fr;
        float bv = bias[col];
        #pragma unroll
        for (int m = 0; m < 4; ++m) {
            #pragma unroll
            for (int j = 0; j < 4; ++j) {
                int row = m0 + wr * 64 + m * 16 + fq * 4 + j;
                float v = acc[m][n][j] + bv;
                if (OUT_F32)
                    reinterpret_cast<float*>(Cout)[(size_t)row * N + col] = v;
                else
                    reinterpret_cast<u16*>(Cout)[(size_t)row * N + col] = f2bf(v);
            }
        }
    }
}

// ------------------------------ flash attention ----------------------------
// Grid: (QL/64, B*H). Block: 256 thr = 4 waves; wave w owns q rows [q0+16w, +16).
// All LDS tiles XOR-swizzled: logical (row, c u16) at row*64 + (c ^ ((row&7)<<3)).
// K staged via global_load_lds with pre-swizzled GLOBAL source (m173 pattern).
// scale = 1/sqrt(D)=1/32 (reference scales by d_model). Causal + key padding.
__global__ __launch_bounds__(256, 2)
void attn_fwd(const u16* __restrict__ Qb, const u16* __restrict__ Kb,
              const u16* __restrict__ Vb, const int* __restrict__ lens,
              u16* __restrict__ Ob) {
    __shared__ __attribute__((aligned(16))) u16 Ks[64 * 64];
    __shared__ __attribute__((aligned(16))) u16 Vts[64 * 64];
    __shared__ __attribute__((aligned(16))) u16 Ps[4][16 * 64];
    const int tid = threadIdx.x, wave = tid >> 6, lane = tid & 63;
    const int qt = (int)gridDim.x - 1 - (int)blockIdx.x;   // longest blocks first
    const int bh = blockIdx.y;
    const int b = bh >> 4, h = bh & 15;
    const int q0 = qt * 64;
    const int fr = lane & 15, fq = lane >> 4;
    const int qrow = q0 + wave * 16;
    const int len = lens[b];

    // Q fragments held in registers (A-frag: row=lane%16, k=(lane/16)*8+j)
    const size_t qoff = (size_t)(b * 2048 + qrow + fr) * 1024 + h * 64 + fq * 8;
    bf16x8 qa0 = *reinterpret_cast<const bf16x8*>(Qb + qoff);
    bf16x8 qa1 = *reinterpret_cast<const bf16x8*>(Qb + qoff + 32);

    float m_s[4], l_s[4];
    f32x4 o_acc[4] = {};
    #pragma unroll
    for (int j = 0; j < 4; ++j) { m_s[j] = -1e30f; l_s[j] = 0.f; }

    const int vk = tid & 63, veg = tid >> 6;  // V^T staging coords
    // K staging: lane's linear LDS slot (l&7)*8 within row holds logical col
    // ((l&7)^(l>>3))*8  ->  pre-swizzle the global source column.
    const int kswz_col = (((lane & 7) ^ (lane >> 3)) * 8);

    for (int kt = 0; kt <= qt; ++kt) {
        const int k0 = kt * 64;
        if (k0 >= len) break;                  // monotone padding: rest all masked
        __syncthreads();                       // previous tile's LDS reads done
        // stage K [64 k][64 e], swizzled, via global_load_lds (1KB per chunk)
        #pragma unroll
        for (int i = 0; i < 2; ++i) {
            int chunk = wave * 2 + i;          // 0..7, 8 k-rows each
            int krow = chunk * 8 + (lane >> 3);
            const u16* gk = Kb + (size_t)(b * 2048 + k0 + krow) * 1024 + h * 64 + kswz_col;
            __builtin_amdgcn_global_load_lds((GLOBAL_AS void*)gk,
                                             (LDS_AS void*)(Ks + chunk * 512), 16, 0, 0);
        }
        // stage V transposed [e][k] through registers, swizzled writes
        #pragma unroll
        for (int i = 0; i < 2; ++i) {
            int e8 = veg + i * 4;              // 0..7 (blocks of 8 e's)
            ushort4 lo = reinterpret_cast<const ushort4*>(
                Vb + (size_t)(b * 2048 + k0 + vk) * 1024 + h * 64 + e8 * 8)[0];
            ushort4 hi = reinterpret_cast<const ushort4*>(
                Vb + (size_t)(b * 2048 + k0 + vk) * 1024 + h * 64 + e8 * 8 + 4)[0];
            Vts[(e8 * 8 + 0) * 64 + (vk ^ 0)]  = lo.x;
            Vts[(e8 * 8 + 1) * 64 + (vk ^ 8)]  = lo.y;
            Vts[(e8 * 8 + 2) * 64 + (vk ^ 16)] = lo.z;
            Vts[(e8 * 8 + 3) * 64 + (vk ^ 24)] = lo.w;
            Vts[(e8 * 8 + 4) * 64 + (vk ^ 32)] = hi.x;
            Vts[(e8 * 8 + 5) * 64 + (vk ^ 40)] = hi.y;
            Vts[(e8 * 8 + 6) * 64 + (vk ^ 48)] = hi.z;
            Vts[(e8 * 8 + 7) * 64 + (vk ^ 56)] = hi.w;
        }
        __syncthreads();

        // S = Q K^T   (B-frag: k=(lane/16)*8+j over e, col=lane&15 over k-tile)
        f32x4 s[4] = {};
        __builtin_amdgcn_s_setprio(1);
        #pragma unroll
        for (int n = 0; n < 4; ++n) {
            int kr = n * 16 + fr;
            int sw = (fr & 7) << 3;
            bf16x8 kb0 = *reinterpret_cast<const bf16x8*>(&Ks[kr * 64 + ((fq * 8) ^ sw)]);
            bf16x8 kb1 = *reinterpret_cast<const bf16x8*>(&Ks[kr * 64 + ((32 + fq * 8) ^ sw)]);
            s[n] = __builtin_amdgcn_mfma_f32_16x16x32_bf16(qa0, kb0, s[n], 0, 0, 0);
            s[n] = __builtin_amdgcn_mfma_f32_16x16x32_bf16(qa1, kb1, s[n], 0, 0, 0);
        }
        __builtin_amdgcn_s_setprio(0);

        // scale + causal/padding mask
        float tmax[4] = {-1e30f, -1e30f, -1e30f, -1e30f};
        #pragma unroll
        for (int n = 0; n < 4; ++n) {
            int kg = k0 + n * 16 + fr;
            bool kv = (kg < len);
            #pragma unroll
            for (int j = 0; j < 4; ++j) {
                int qg = qrow + fq * 4 + j;
                float sc = s[n][j] * 0.03125f;
                sc = (kv && kg <= qg) ? sc : -1e30f;
                s[n][j] = sc;
                tmax[j] = fmaxf(tmax[j], sc);
            }
        }
        // row max across the 16 lanes of each row-group
        #pragma unroll
        for (int off = 1; off < 16; off <<= 1)
            #pragma unroll
            for (int j = 0; j < 4; ++j)
                tmax[j] = fmaxf(tmax[j], __shfl_xor(tmax[j], off));
        float rs[4];
        #pragma unroll
        for (int j = 0; j < 4; ++j) {
            float mn = fmaxf(m_s[j], tmax[j]);
            float f = __expf(m_s[j] - mn);
            m_s[j] = mn; l_s[j] *= f; rs[j] = 0.f;
            #pragma unroll
            for (int n = 0; n < 4; ++n) o_acc[n][j] *= f;
        }
        #pragma unroll
        for (int n = 0; n < 4; ++n)
            #pragma unroll
            for (int j = 0; j < 4; ++j) {
                float p = __expf(s[n][j] - m_s[j]);
                s[n][j] = p; rs[j] += p;
            }
        #pragma unroll
        for (int off = 1; off < 16; off <<= 1)
            #pragma unroll
            for (int j = 0; j < 4; ++j)
                rs[j] += __shfl_xor(rs[j], off);
        #pragma unroll
        for (int j = 0; j < 4; ++j) l_s[j] += rs[j];

        // P (bf16) -> per-wave LDS [q 16][k 64], swizzled writes
        #pragma unroll
        for (int n = 0; n < 4; ++n)
            #pragma unroll
            for (int j = 0; j < 4; ++j) {
                int prow = fq * 4 + j;
                Ps[wave][prow * 64 + ((n * 16 + fr) ^ ((prow & 7) << 3))] = f2bf(s[n][j]);
            }

        // O += P V   (A-frag from Ps, B-frag from Vts rows = contiguous k)
        __builtin_amdgcn_s_setprio(1);
        #pragma unroll
        for (int ks = 0; ks < 2; ++ks) {
            bf16x8 pa = *reinterpret_cast<const bf16x8*>(
                &Ps[wave][fr * 64 + ((ks * 32 + fq * 8) ^ ((fr & 7) << 3))]);
            #pragma unroll
            for (int n = 0; n < 4; ++n) {
                int vr = n * 16 + fr;
                bf16x8 vb2 = *reinterpret_cast<const bf16x8*>(
                    &Vts[vr * 64 + ((ks * 32 + fq * 8) ^ ((fr & 7) << 3))]);
                o_acc[n] = __builtin_amdgcn_mfma_f32_16x16x32_bf16(pa, vb2, o_acc[n], 0, 0, 0);
            }
        }
        __builtin_amdgcn_s_setprio(0);
    }

    // epilogue: O / l  -> agg [B*L, D] bf16
    #pragma unroll
    for (int j = 0; j < 4; ++j) {
        float inv = 1.f / l_s[j];
        int row = qrow + fq * 4 + j;
        #pragma unroll
        for (int n = 0; n < 4; ++n) {
            int col = h * 64 + n * 16 + fr;
            Ob[(size_t)(b * 2048 + row) * 1024 + col] = f2bf(o_acc[n][j] * inv);
        }
    }
}

// ------------------------------ launch -------------------------------------
extern "C" void kernel_launch(void* const* d_in, const int* in_sizes, int n_in,
                              void* d_out, int out_size, void* d_ws, size_t ws_size,
                              hipStream_t stream) {
    const float* xq_f = (const float*)d_in[0];
    const float* xk_f = (const float*)d_in[1];
    // d_in[2] = dependency_mask (causal, reimplemented analytically)
    const int* kpm = (const int*)d_in[3];
    const float* Wq = (const float*)d_in[4];
    const float* bq = (const float*)d_in[5];
    const float* Wk = (const float*)d_in[6];
    const float* bk = (const float*)d_in[7];
    const float* Wv = (const float*)d_in[8];
    const float* bv = (const float*)d_in[9];
    const float* Wo = (const float*)d_in[10];
    const float* bo = (const float*)d_in[11];

    u16* ws = (u16*)d_ws;
    u16* xq = ws;                  // 4096x1024
    u16* xk = xq + 4194304;        // 4096x1024
    u16* wq = xk + 4194304;        // 1024x1024
    u16* wk = wq + 1048576;
    u16* wv = wk + 1048576;
    u16* wo = wv + 1048576;
    u16* qb = wo + 1048576;        // 4096x1024
    u16* kb2 = qb + 4194304;
    u16* vb2 = kb2 + 4194304;
    u16* ag = vb2 + 4194304;       // 4096x1024
    int* lens = (int*)(ag + 4194304);  // 2 ints

    compute_lens<<<2, 1024, 0, stream>>>(kpm, lens);

    cvt_bf16<<<4096, 256, 0, stream>>>(xq_f, xq, 1048576);
    cvt_bf16<<<4096, 256, 0, stream>>>(xk_f, xk, 1048576);
    cvt_bf16<<<1024, 256, 0, stream>>>(Wq, wq, 262144);
    cvt_bf16<<<1024, 256, 0, stream>>>(Wk, wk, 262144);
    cvt_bf16<<<1024, 256, 0, stream>>>(Wv, wv, 262144);
    cvt_bf16<<<1024, 256, 0, stream>>>(Wo, wo, 262144);

    dim3 gg(8, 32);  // N/128, M/128
    gemm_bt<0><<<gg, 256, 0, stream>>>(xq, wq, bq, qb, 4096, 1024, 1024);
    gemm_bt<0><<<gg, 256, 0, stream>>>(xk, wk, bk, kb2, 4096, 1024, 1024);
    gemm_bt<0><<<gg, 256, 0, stream>>>(xk, wv, bv, vb2, 4096, 1024, 1024);

    attn_fwd<<<dim3(32, 32), 256, 0, stream>>>(qb, kb2, vb2, lens, ag);

    gemm_bt<1><<<gg, 256, 0, stream>>>(ag, wo, bo, (float*)d_out, 4096, 1024, 1024);
}

// Round 3
// 167.145 us; speedup vs baseline: 1.6068x; 1.4026x over previous
//
#include <hip/hip_runtime.h>
#include <hip/hip_bf16.h>

// ---------------------------------------------------------------------------
// Self-attention MH: B=2, QL=KL=2048, D=1024, H=16, E=64.
// R3: attn dbuf K/V + async-stage split (T14), 1 barrier/tile, defer-rescale
//     (T13), deferred l-reduce, full-tile mask skip, scale folded into Q-proj,
//     fused QKV GEMM (3 blocks/CU), single fused convert kernel.
// ---------------------------------------------------------------------------

typedef __bf16 bf16x8 __attribute__((ext_vector_type(8)));
typedef float f32x4 __attribute__((ext_vector_type(4)));
typedef unsigned short u16;

#define GLOBAL_AS __attribute__((address_space(1)))
#define LDS_AS __attribute__((address_space(3)))

static __device__ __forceinline__ u16 f2bf(float f) {
    __hip_bfloat16 h = __float2bfloat16(f);
    return __builtin_bit_cast(u16, h);
}

// ------------------------------ fused f32 -> bf16 --------------------------
// Segments (float4 units): xq 1048576 (4096 blk), xk 1048576 (4096 blk),
// wq/wk/wv/wo 262144 each (1024 blk each). Total 12288 blocks x 256 thr.
__global__ void cvt_all(const float* __restrict__ xq_f, const float* __restrict__ xk_f,
                        const float* __restrict__ wq_f, const float* __restrict__ wk_f,
                        const float* __restrict__ wv_f, const float* __restrict__ wo_f,
                        u16* __restrict__ xq, u16* __restrict__ xk,
                        u16* __restrict__ wq, u16* __restrict__ wk,
                        u16* __restrict__ wv, u16* __restrict__ wo) {
    int blk = blockIdx.x;
    const float* s; u16* d; int i;
    if (blk < 4096)      { s = xq_f; d = xq; i = blk * 256 + threadIdx.x; }
    else if (blk < 8192) { s = xk_f; d = xk; i = (blk - 4096) * 256 + threadIdx.x; }
    else {
        int wsel = (blk - 8192) >> 10;
        i = ((blk - 8192) & 1023) * 256 + threadIdx.x;
        if (wsel == 0)      { s = wq_f; d = wq; }
        else if (wsel == 1) { s = wk_f; d = wk; }
        else if (wsel == 2) { s = wv_f; d = wv; }
        else                { s = wo_f; d = wo; }
    }
    float4 v = reinterpret_cast<const float4*>(s)[i];
    ushort4 o;
    o.x = f2bf(v.x); o.y = f2bf(v.y); o.z = f2bf(v.z); o.w = f2bf(v.w);
    reinterpret_cast<ushort4*>(d)[i] = o;
}

// ---------------------- padding lengths (monotone mask) --------------------
__global__ void compute_lens(const int* __restrict__ kpm, int* __restrict__ lens) {
    const int b = blockIdx.x, tid = threadIdx.x;   // 1024 threads
    int cnt = 0;
    for (int i = tid; i < 2048; i += 1024) cnt += (kpm[b * 2048 + i] == 0) ? 1 : 0;
    #pragma unroll
    for (int off = 32; off; off >>= 1) cnt += __shfl_down(cnt, off);
    __shared__ int wsum[16];
    if ((tid & 63) == 0) wsum[tid >> 6] = cnt;
    __syncthreads();
    if (tid == 0) {
        int t = 0;
        #pragma unroll
        for (int w = 0; w < 16; ++w) t += wsum[w];
        lens[b] = t;
    }
}

// ------------------------------ GEMM body: C = (A*B^T + bias)*scale --------
// A [M,K] row-major bf16, Bw [N,K] row-major bf16, bias[N] f32.
// 128x128 tile, BK=32, 4 waves (2x2), each wave 64x64 (4x4 frags of 16x16x32).
template<int OUT_F32>
__device__ __forceinline__
void gemm_body(const u16* __restrict__ A, const u16* __restrict__ Bw,
               const float* __restrict__ bias, void* __restrict__ Cout,
               int N, int K, float scale, int bx, int by) {
    __shared__ __attribute__((aligned(16))) u16 aS[128 * 32];
    __shared__ __attribute__((aligned(16))) u16 bS[128 * 32];
    const int tid = threadIdx.x, wave = tid >> 6, lane = tid & 63;
    const int m0 = by * 128, n0 = bx * 128;
    const int wr = wave >> 1, wc = wave & 1;
    const int lrow = lane >> 2, lcol = (lane & 3) * 8;   // staging row/col in tile
    const int fr = lane & 15, fq = lane >> 4;            // fragment coords

    f32x4 acc[4][4] = {};

    for (int k0 = 0; k0 < K; k0 += 32) {
        #pragma unroll
        for (int i = 0; i < 2; ++i) {
            int chunk = wave * 2 + i;            // 0..7, 16 rows each
            int row = chunk * 16 + lrow;
            const u16* ga = A + (size_t)(m0 + row) * K + k0 + lcol;
            const u16* gb = Bw + (size_t)(n0 + row) * K + k0 + lcol;
            __builtin_amdgcn_global_load_lds((GLOBAL_AS void*)ga,
                                             (LDS_AS void*)(aS + chunk * 512), 16, 0, 0);
            __builtin_amdgcn_global_load_lds((GLOBAL_AS void*)gb,
                                             (LDS_AS void*)(bS + chunk * 512), 16, 0, 0);
        }
        __syncthreads();
        bf16x8 af[4], bfr[4];
        #pragma unroll
        for (int m = 0; m < 4; ++m)
            af[m] = *reinterpret_cast<const bf16x8*>(&aS[(wr * 64 + m * 16 + fr) * 32 + fq * 8]);
        #pragma unroll
        for (int n = 0; n < 4; ++n)
            bfr[n] = *reinterpret_cast<const bf16x8*>(&bS[(wc * 64 + n * 16 + fr) * 32 + fq * 8]);
        #pragma unroll
        for (int m = 0; m < 4; ++m)
            #pragma unroll
            for (int n = 0; n < 4; ++n)
                acc[m][n] = __builtin_amdgcn_mfma_f32_16x16x32_bf16(af[m], bfr[n], acc[m][n], 0, 0, 0);
        __syncthreads();
    }

    // epilogue: C/D layout col=lane&15, row=(lane>>4)*4+j  [verified m89/m91]
    #pragma unroll
    for (int n = 0; n < 4; ++n) {
        int col = n0 + wc * 64 + n * 16 + fr;
        float bv = bias[col];
        #pragma unroll
        for (int m = 0; m < 4; ++m) {
            #pragma unroll
            for (int j = 0; j < 4; ++j) {
                int row = m0 + wr * 64 + m * 16 + fq * 4 + j;
                float v = (acc[m][n][j] + bv) * scale;
                if (OUT_F32)
                    reinterpret_cast<float*>(Cout)[(size_t)row * N + col] = v;
                else
                    reinterpret_cast<u16*>(Cout)[(size_t)row * N + col] = f2bf(v);
            }
        }
    }
}

// Fused Q/K/V projection: grid (8, 32, 3); z selects A/W/bias/out.
// Q output pre-scaled by 1/sqrt(D)=1/32 (reference scales scores by d_model).
__global__ __launch_bounds__(256, 2)
void gemm_qkv(const u16* __restrict__ xq, const u16* __restrict__ xk,
              const u16* __restrict__ wq, const u16* __restrict__ wk,
              const u16* __restrict__ wv,
              const float* __restrict__ bq, const float* __restrict__ bk,
              const float* __restrict__ bv,
              u16* __restrict__ qb, u16* __restrict__ kb, u16* __restrict__ vb) {
    const int z = blockIdx.z;
    const u16* A = (z == 0) ? xq : xk;
    const u16* W = (z == 0) ? wq : (z == 1) ? wk : wv;
    const float* bias = (z == 0) ? bq : (z == 1) ? bk : bv;
    u16* C = (z == 0) ? qb : (z == 1) ? kb : vb;
    const float scale = (z == 0) ? 0.03125f : 1.0f;
    gemm_body<0>(A, W, bias, C, 1024, 1024, scale, blockIdx.x, blockIdx.y);
}

__global__ __launch_bounds__(256, 2)
void gemm_out(const u16* __restrict__ A, const u16* __restrict__ Bw,
              const float* __restrict__ bias, float* __restrict__ Cout) {
    gemm_body<1>(A, Bw, bias, Cout, 1024, 1024, 1.0f, blockIdx.x, blockIdx.y);
}

// ------------------------------ flash attention ----------------------------
// Grid: (QL/64, B*H). Block: 256 thr = 4 waves; wave w owns q rows [q0+16w, +16).
// Double-buffered K/V tiles, async-stage split (issue early / V-write late),
// one barrier per tile. LDS XOR-swizzled (row,c): row*64 + (c ^ ((row&7)<<3)).
// Q is pre-scaled by 1/32 in the projection. Causal + key padding via lens.
__global__ __launch_bounds__(256, 2)
void attn_fwd(const u16* __restrict__ Qb, const u16* __restrict__ Kb,
              const u16* __restrict__ Vb, const int* __restrict__ lens,
              u16* __restrict__ Ob) {
    __shared__ __attribute__((aligned(16))) u16 Ks[2][64 * 64];
    __shared__ __attribute__((aligned(16))) u16 Vts[2][64 * 64];
    __shared__ __attribute__((aligned(16))) u16 Ps[4][16 * 64];
    const int tid = threadIdx.x, wave = tid >> 6, lane = tid & 63;
    const int qt = (int)gridDim.x - 1 - (int)blockIdx.x;   // longest blocks first
    const int bh = blockIdx.y;
    const int b = bh >> 4, h = bh & 15;
    const int q0 = qt * 64;
    const int fr = lane & 15, fq = lane >> 4;
    const int qrow = q0 + wave * 16;
    const int len = lens[b];
    const int nt = min(qt + 1, (len + 63) >> 6);

    // Q fragments held in registers (A-frag: row=lane%16, k=(lane/16)*8+j)
    const size_t qoff = (size_t)(b * 2048 + qrow + fr) * 1024 + h * 64 + fq * 8;
    bf16x8 qa0 = *reinterpret_cast<const bf16x8*>(Qb + qoff);
    bf16x8 qa1 = *reinterpret_cast<const bf16x8*>(Qb + qoff + 32);

    float m_s[4], l_s[4];
    f32x4 o_acc[4] = {};
    #pragma unroll
    for (int j = 0; j < 4; ++j) { m_s[j] = -1e30f; l_s[j] = 0.f; }

    const int vk = tid & 63, veg = tid >> 6;  // V^T staging coords
    // K staging: linear LDS dest; pre-swizzle the GLOBAL source column (m173).
    const int kswz_col = (((lane & 7) ^ (lane >> 3)) * 8);

    auto issue_K = [&](int kt, int buf) {
        #pragma unroll
        for (int i = 0; i < 2; ++i) {
            int chunk = wave * 2 + i;          // 0..7, 8 k-rows each
            int krow = chunk * 8 + (lane >> 3);
            const u16* gk = Kb + (size_t)(b * 2048 + kt * 64 + krow) * 1024 + h * 64 + kswz_col;
            __builtin_amdgcn_global_load_lds((GLOBAL_AS void*)gk,
                                             (LDS_AS void*)(&Ks[buf][chunk * 512]), 16, 0, 0);
        }
    };
    auto load_V = [&](int kt, ushort4* r) {
        const u16* base = Vb + (size_t)(b * 2048 + kt * 64 + vk) * 1024 + h * 64;
        r[0] = reinterpret_cast<const ushort4*>(base + veg * 8)[0];
        r[1] = reinterpret_cast<const ushort4*>(base + veg * 8 + 4)[0];
        r[2] = reinterpret_cast<const ushort4*>(base + (veg + 4) * 8)[0];
        r[3] = reinterpret_cast<const ushort4*>(base + (veg + 4) * 8 + 4)[0];
    };
    auto write_V = [&](const ushort4* r, int buf) {
        #pragma unroll
        for (int i = 0; i < 2; ++i) {
            int e8 = veg + i * 4;
            ushort4 lo = r[i * 2], hi = r[i * 2 + 1];
            u16* base = &Vts[buf][e8 * 8 * 64];
            base[0 * 64 + (vk ^ 0)]  = lo.x;
            base[1 * 64 + (vk ^ 8)]  = lo.y;
            base[2 * 64 + (vk ^ 16)] = lo.z;
            base[3 * 64 + (vk ^ 24)] = lo.w;
            base[4 * 64 + (vk ^ 32)] = hi.x;
            base[5 * 64 + (vk ^ 40)] = hi.y;
            base[6 * 64 + (vk ^ 48)] = hi.z;
            base[7 * 64 + (vk ^ 56)] = hi.w;
        }
    };

    // prologue: stage tile 0 into buf 0
    {
        ushort4 vr[4];
        issue_K(0, 0);
        load_V(0, vr);
        write_V(vr, 0);
    }
    __syncthreads();

    for (int kt = 0; kt < nt; ++kt) {
        const int k0 = kt * 64;
        const int cur = kt & 1, nxt = cur ^ 1;
        const bool has_next = (kt + 1 < nt);

        // issue next tile's staging loads early (hide under compute)
        ushort4 vr[4];
        if (has_next) {
            issue_K(kt + 1, nxt);
            load_V(kt + 1, vr);
        }

        // S = Q K^T   (B-frag: k=(lane/16)*8+j over e, col=lane&15 over k-tile)
        f32x4 s[4] = {};
        __builtin_amdgcn_s_setprio(1);
        #pragma unroll
        for (int n = 0; n < 4; ++n) {
            int kr = n * 16 + fr;
            int sw = (fr & 7) << 3;
            bf16x8 kb0 = *reinterpret_cast<const bf16x8*>(&Ks[cur][kr * 64 + ((fq * 8) ^ sw)]);
            bf16x8 kb1 = *reinterpret_cast<const bf16x8*>(&Ks[cur][kr * 64 + ((32 + fq * 8) ^ sw)]);
            s[n] = __builtin_amdgcn_mfma_f32_16x16x32_bf16(qa0, kb0, s[n], 0, 0, 0);
            s[n] = __builtin_amdgcn_mfma_f32_16x16x32_bf16(qa1, kb1, s[n], 0, 0, 0);
        }
        __builtin_amdgcn_s_setprio(0);

        // mask (skipped on interior full tiles) + per-row tile max
        float tmax[4] = {-1e30f, -1e30f, -1e30f, -1e30f};
        const bool fullt = (k0 + 63 <= qrow) && (k0 + 64 <= len);
        if (fullt) {
            #pragma unroll
            for (int n = 0; n < 4; ++n)
                #pragma unroll
                for (int j = 0; j < 4; ++j)
                    tmax[j] = fmaxf(tmax[j], s[n][j]);
        } else {
            #pragma unroll
            for (int n = 0; n < 4; ++n) {
                int kg = k0 + n * 16 + fr;
                bool kv = (kg < len);
                #pragma unroll
                for (int j = 0; j < 4; ++j) {
                    int qg = qrow + fq * 4 + j;
                    float sc = s[n][j];
                    sc = (kv && kg <= qg) ? sc : -1e30f;
                    s[n][j] = sc;
                    tmax[j] = fmaxf(tmax[j], sc);
                }
            }
        }
        // row max across the 16 lanes of each row-group
        #pragma unroll
        for (int off = 1; off < 16; off <<= 1)
            #pragma unroll
            for (int j = 0; j < 4; ++j)
                tmax[j] = fmaxf(tmax[j], __shfl_xor(tmax[j], off));

        // defer-max (T13): only rescale when the max grew past threshold 8
        bool need = false;
        #pragma unroll
        for (int j = 0; j < 4; ++j) need |= (tmax[j] > m_s[j] + 8.f);
        if (__any(need)) {
            #pragma unroll
            for (int j = 0; j < 4; ++j) {
                float mn = fmaxf(m_s[j], tmax[j]);
                float f = __expf(m_s[j] - mn);
                m_s[j] = mn; l_s[j] *= f;
                #pragma unroll
                for (int n = 0; n < 4; ++n) o_acc[n][j] *= f;
            }
        }
        // P = exp(S - m); l accumulates PER-LANE partials (reduced in epilogue)
        #pragma unroll
        for (int n = 0; n < 4; ++n)
            #pragma unroll
            for (int j = 0; j < 4; ++j) {
                float p = __expf(s[n][j] - m_s[j]);
                s[n][j] = p; l_s[j] += p;
            }

        // P (bf16) -> per-wave LDS [q 16][k 64], swizzled writes
        #pragma unroll
        for (int n = 0; n < 4; ++n)
            #pragma unroll
            for (int j = 0; j < 4; ++j) {
                int prow = fq * 4 + j;
                Ps[wave][prow * 64 + ((n * 16 + fr) ^ ((prow & 7) << 3))] = f2bf(s[n][j]);
            }

        // O += P V   (A-frag from Ps, B-frag from Vts rows = contiguous k)
        __builtin_amdgcn_s_setprio(1);
        #pragma unroll
        for (int ks = 0; ks < 2; ++ks) {
            bf16x8 pa = *reinterpret_cast<const bf16x8*>(
                &Ps[wave][fr * 64 + ((ks * 32 + fq * 8) ^ ((fr & 7) << 3))]);
            #pragma unroll
            for (int n = 0; n < 4; ++n) {
                int vr2 = n * 16 + fr;
                bf16x8 vb2 = *reinterpret_cast<const bf16x8*>(
                    &Vts[cur][vr2 * 64 + ((ks * 32 + fq * 8) ^ ((fr & 7) << 3))]);
                o_acc[n] = __builtin_amdgcn_mfma_f32_16x16x32_bf16(pa, vb2, o_acc[n], 0, 0, 0);
            }
        }
        __builtin_amdgcn_s_setprio(0);

        // late half of the async stage: V regs -> LDS for next tile
        if (has_next) write_V(vr, nxt);
        __syncthreads();
    }

    // epilogue: reduce l across the 16-lane row groups, then O / l
    #pragma unroll
    for (int off = 1; off < 16; off <<= 1)
        #pragma unroll
        for (int j = 0; j < 4; ++j)
            l_s[j] += __shfl_xor(l_s[j], off);
    #pragma unroll
    for (int j = 0; j < 4; ++j) {
        float inv = 1.f / l_s[j];
        int row = qrow + fq * 4 + j;
        #pragma unroll
        for (int n = 0; n < 4; ++n) {
            int col = h * 64 + n * 16 + fr;
            Ob[(size_t)(b * 2048 + row) * 1024 + col] = f2bf(o_acc[n][j] * inv);
        }
    }
}

// ------------------------------ launch -------------------------------------
extern "C" void kernel_launch(void* const* d_in, const int* in_sizes, int n_in,
                              void* d_out, int out_size, void* d_ws, size_t ws_size,
                              hipStream_t stream) {
    const float* xq_f = (const float*)d_in[0];
    const float* xk_f = (const float*)d_in[1];
    // d_in[2] = dependency_mask (causal, reimplemented analytically)
    const int* kpm = (const int*)d_in[3];
    const float* Wq = (const float*)d_in[4];
    const float* bq = (const float*)d_in[5];
    const float* Wk = (const float*)d_in[6];
    const float* bk = (const float*)d_in[7];
    const float* Wv = (const float*)d_in[8];
    const float* bv = (const float*)d_in[9];
    const float* Wo = (const float*)d_in[10];
    const float* bo = (const float*)d_in[11];

    u16* ws = (u16*)d_ws;
    u16* xq = ws;                  // 4096x1024
    u16* xk = xq + 4194304;        // 4096x1024
    u16* wq = xk + 4194304;        // 1024x1024
    u16* wk = wq + 1048576;
    u16* wv = wk + 1048576;
    u16* wo = wv + 1048576;
    u16* qb = wo + 1048576;        // 4096x1024
    u16* kb2 = qb + 4194304;
    u16* vb2 = kb2 + 4194304;
    u16* ag = vb2 + 4194304;       // 4096x1024
    int* lens = (int*)(ag + 4194304);  // 2 ints

    compute_lens<<<2, 1024, 0, stream>>>(kpm, lens);
    cvt_all<<<12288, 256, 0, stream>>>(xq_f, xk_f, Wq, Wk, Wv, Wo,
                                       xq, xk, wq, wk, wv, wo);

    gemm_qkv<<<dim3(8, 32, 3), 256, 0, stream>>>(xq, xk, wq, wk, wv,
                                                 bq, bk, bv, qb, kb2, vb2);

    attn_fwd<<<dim3(32, 32), 256, 0, stream>>>(qb, kb2, vb2, lens, ag);

    gemm_out<<<dim3(8, 32), 256, 0, stream>>>(ag, wo, bo, (float*)d_out);
}

// Round 4
// 136.709 us; speedup vs baseline: 1.9646x; 1.2226x over previous
//
#include <hip/hip_runtime.h>
#include <hip/hip_bf16.h>

// ---------------------------------------------------------------------------
// Self-attention MH: B=2, QL=KL=2048, D=1024, H=16, E=64.
// R4: per-CU load-balanced qt mapping (CU-mates' qts sum to 62), DPP 16-lane
//     reductions (no LDS-pipe shuffles), 4 blocks/CU attn occupancy.
// ---------------------------------------------------------------------------

typedef __bf16 bf16x8 __attribute__((ext_vector_type(8)));
typedef float f32x4 __attribute__((ext_vector_type(4)));
typedef unsigned short u16;

#define GLOBAL_AS __attribute__((address_space(1)))
#define LDS_AS __attribute__((address_space(3)))

static __device__ __forceinline__ u16 f2bf(float f) {
    __hip_bfloat16 h = __float2bfloat16(f);
    return __builtin_bit_cast(u16, h);
}

// DPP cross-lane reduce helpers (16-lane groups): quad_perm xor1 (0xB1),
// quad_perm xor2 (0x4E), row_half_mirror (0x141), row_mirror (0x140).
template<int CTRL>
static __device__ __forceinline__ float dpp_mov(float x) {
    return __builtin_bit_cast(float, __builtin_amdgcn_update_dpp(
        0, __builtin_bit_cast(int, x), CTRL, 0xF, 0xF, true));
}
static __device__ __forceinline__ float red16_max(float t) {
    t = fmaxf(t, dpp_mov<0xB1>(t));
    t = fmaxf(t, dpp_mov<0x4E>(t));
    t = fmaxf(t, dpp_mov<0x141>(t));
    t = fmaxf(t, dpp_mov<0x140>(t));
    return t;
}
static __device__ __forceinline__ float red16_sum(float t) {
    t = t + dpp_mov<0xB1>(t);
    t = t + dpp_mov<0x4E>(t);
    t = t + dpp_mov<0x141>(t);
    t = t + dpp_mov<0x140>(t);
    return t;
}

// ------------------------------ fused f32 -> bf16 --------------------------
__global__ void cvt_all(const float* __restrict__ xq_f, const float* __restrict__ xk_f,
                        const float* __restrict__ wq_f, const float* __restrict__ wk_f,
                        const float* __restrict__ wv_f, const float* __restrict__ wo_f,
                        u16* __restrict__ xq, u16* __restrict__ xk,
                        u16* __restrict__ wq, u16* __restrict__ wk,
                        u16* __restrict__ wv, u16* __restrict__ wo) {
    int blk = blockIdx.x;
    const float* s; u16* d; int i;
    if (blk < 4096)      { s = xq_f; d = xq; i = blk * 256 + threadIdx.x; }
    else if (blk < 8192) { s = xk_f; d = xk; i = (blk - 4096) * 256 + threadIdx.x; }
    else {
        int wsel = (blk - 8192) >> 10;
        i = ((blk - 8192) & 1023) * 256 + threadIdx.x;
        if (wsel == 0)      { s = wq_f; d = wq; }
        else if (wsel == 1) { s = wk_f; d = wk; }
        else if (wsel == 2) { s = wv_f; d = wv; }
        else                { s = wo_f; d = wo; }
    }
    float4 v = reinterpret_cast<const float4*>(s)[i];
    ushort4 o;
    o.x = f2bf(v.x); o.y = f2bf(v.y); o.z = f2bf(v.z); o.w = f2bf(v.w);
    reinterpret_cast<ushort4*>(d)[i] = o;
}

// ---------------------- padding lengths (monotone mask) --------------------
__global__ void compute_lens(const int* __restrict__ kpm, int* __restrict__ lens) {
    const int b = blockIdx.x, tid = threadIdx.x;   // 1024 threads
    int cnt = 0;
    for (int i = tid; i < 2048; i += 1024) cnt += (kpm[b * 2048 + i] == 0) ? 1 : 0;
    #pragma unroll
    for (int off = 32; off; off >>= 1) cnt += __shfl_down(cnt, off);
    __shared__ int wsum[16];
    if ((tid & 63) == 0) wsum[tid >> 6] = cnt;
    __syncthreads();
    if (tid == 0) {
        int t = 0;
        #pragma unroll
        for (int w = 0; w < 16; ++w) t += wsum[w];
        lens[b] = t;
    }
}

// ------------------------------ GEMM body: C = (A*B^T + bias)*scale --------
template<int OUT_F32>
__device__ __forceinline__
void gemm_body(const u16* __restrict__ A, const u16* __restrict__ Bw,
               const float* __restrict__ bias, void* __restrict__ Cout,
               int N, int K, float scale, int bx, int by) {
    __shared__ __attribute__((aligned(16))) u16 aS[128 * 32];
    __shared__ __attribute__((aligned(16))) u16 bS[128 * 32];
    const int tid = threadIdx.x, wave = tid >> 6, lane = tid & 63;
    const int m0 = by * 128, n0 = bx * 128;
    const int wr = wave >> 1, wc = wave & 1;
    const int lrow = lane >> 2, lcol = (lane & 3) * 8;
    const int fr = lane & 15, fq = lane >> 4;

    f32x4 acc[4][4] = {};

    for (int k0 = 0; k0 < K; k0 += 32) {
        #pragma unroll
        for (int i = 0; i < 2; ++i) {
            int chunk = wave * 2 + i;
            int row = chunk * 16 + lrow;
            const u16* ga = A + (size_t)(m0 + row) * K + k0 + lcol;
            const u16* gb = Bw + (size_t)(n0 + row) * K + k0 + lcol;
            __builtin_amdgcn_global_load_lds((GLOBAL_AS void*)ga,
                                             (LDS_AS void*)(aS + chunk * 512), 16, 0, 0);
            __builtin_amdgcn_global_load_lds((GLOBAL_AS void*)gb,
                                             (LDS_AS void*)(bS + chunk * 512), 16, 0, 0);
        }
        __syncthreads();
        bf16x8 af[4], bfr[4];
        #pragma unroll
        for (int m = 0; m < 4; ++m)
            af[m] = *reinterpret_cast<const bf16x8*>(&aS[(wr * 64 + m * 16 + fr) * 32 + fq * 8]);
        #pragma unroll
        for (int n = 0; n < 4; ++n)
            bfr[n] = *reinterpret_cast<const bf16x8*>(&bS[(wc * 64 + n * 16 + fr) * 32 + fq * 8]);
        #pragma unroll
        for (int m = 0; m < 4; ++m)
            #pragma unroll
            for (int n = 0; n < 4; ++n)
                acc[m][n] = __builtin_amdgcn_mfma_f32_16x16x32_bf16(af[m], bfr[n], acc[m][n], 0, 0, 0);
        __syncthreads();
    }

    #pragma unroll
    for (int n = 0; n < 4; ++n) {
        int col = n0 + wc * 64 + n * 16 + fr;
        float bv = bias[col];
        #pragma unroll
        for (int m = 0; m < 4; ++m) {
            #pragma unroll
            for (int j = 0; j < 4; ++j) {
                int row = m0 + wr * 64 + m * 16 + fq * 4 + j;
                float v = (acc[m][n][j] + bv) * scale;
                if (OUT_F32)
                    reinterpret_cast<float*>(Cout)[(size_t)row * N + col] = v;
                else
                    reinterpret_cast<u16*>(Cout)[(size_t)row * N + col] = f2bf(v);
            }
        }
    }
}

// Fused Q/K/V projection; Q pre-scaled by 1/32 (reference scales by d_model).
__global__ __launch_bounds__(256, 2)
void gemm_qkv(const u16* __restrict__ xq, const u16* __restrict__ xk,
              const u16* __restrict__ wq, const u16* __restrict__ wk,
              const u16* __restrict__ wv,
              const float* __restrict__ bq, const float* __restrict__ bk,
              const float* __restrict__ bv,
              u16* __restrict__ qb, u16* __restrict__ kb, u16* __restrict__ vb) {
    const int z = blockIdx.z;
    const u16* A = (z == 0) ? xq : xk;
    const u16* W = (z == 0) ? wq : (z == 1) ? wk : wv;
    const float* bias = (z == 0) ? bq : (z == 1) ? bk : bv;
    u16* C = (z == 0) ? qb : (z == 1) ? kb : vb;
    const float scale = (z == 0) ? 0.03125f : 1.0f;
    gemm_body<0>(A, W, bias, C, 1024, 1024, scale, blockIdx.x, blockIdx.y);
}

__global__ __launch_bounds__(256, 2)
void gemm_out(const u16* __restrict__ A, const u16* __restrict__ Bw,
              const float* __restrict__ bias, float* __restrict__ Cout) {
    gemm_body<1>(A, Bw, bias, Cout, 1024, 1024, 1.0f, blockIdx.x, blockIdx.y);
}

// ------------------------------ flash attention ----------------------------
// Grid (32, 32): y = bh; x -> qt via per-CU-balanced mapping (CU-mates are
// ids 256 apart = same x, y differing by 8; their 4 qts sum to 62 so every
// CU gets 66 tile-units). Double-buffered K/V, async-stage split, 1 barrier
// per tile, DPP reductions, defer-rescale. LDS XOR-swizzle (row&7)<<3.
__global__ __launch_bounds__(256, 4)
void attn_fwd(const u16* __restrict__ Qb, const u16* __restrict__ Kb,
              const u16* __restrict__ Vb, const int* __restrict__ lens,
              u16* __restrict__ Ob) {
    __shared__ __attribute__((aligned(16))) u16 Ks[2][64 * 64];
    __shared__ __attribute__((aligned(16))) u16 Vts[2][64 * 64];
    __shared__ __attribute__((aligned(16))) u16 Ps[4][16 * 64];
    const int tid = threadIdx.x, wave = tid >> 6, lane = tid & 63;
    const int x = blockIdx.x, y = blockIdx.y;
    const int g = (y >> 3) & 3;
    int qt;
    if (g == 0)      qt = x;
    else if (g == 1) qt = 31 - x;
    else if (g == 2) qt = (x + 16) & 31;
    else             qt = 31 - ((x + 16) & 31);
    const int b = y >> 4, h = y & 15;
    const int q0 = qt * 64;
    const int fr = lane & 15, fq = lane >> 4;
    const int qrow = q0 + wave * 16;
    const int len = lens[b];
    const int nt = min(qt + 1, (len + 63) >> 6);

    const size_t qoff = (size_t)(b * 2048 + qrow + fr) * 1024 + h * 64 + fq * 8;
    bf16x8 qa0 = *reinterpret_cast<const bf16x8*>(Qb + qoff);
    bf16x8 qa1 = *reinterpret_cast<const bf16x8*>(Qb + qoff + 32);

    float m_s[4], l_s[4];
    f32x4 o_acc[4] = {};
    #pragma unroll
    for (int j = 0; j < 4; ++j) { m_s[j] = -1e30f; l_s[j] = 0.f; }

    const int vk = tid & 63, veg = tid >> 6;
    const int kswz_col = (((lane & 7) ^ (lane >> 3)) * 8);

    auto issue_K = [&](int kt, int buf) {
        #pragma unroll
        for (int i = 0; i < 2; ++i) {
            int chunk = wave * 2 + i;
            int krow = chunk * 8 + (lane >> 3);
            const u16* gk = Kb + (size_t)(b * 2048 + kt * 64 + krow) * 1024 + h * 64 + kswz_col;
            __builtin_amdgcn_global_load_lds((GLOBAL_AS void*)gk,
                                             (LDS_AS void*)(&Ks[buf][chunk * 512]), 16, 0, 0);
        }
    };
    auto load_V = [&](int kt, ushort4* r) {
        const u16* base = Vb + (size_t)(b * 2048 + kt * 64 + vk) * 1024 + h * 64;
        r[0] = reinterpret_cast<const ushort4*>(base + veg * 8)[0];
        r[1] = reinterpret_cast<const ushort4*>(base + veg * 8 + 4)[0];
        r[2] = reinterpret_cast<const ushort4*>(base + (veg + 4) * 8)[0];
        r[3] = reinterpret_cast<const ushort4*>(base + (veg + 4) * 8 + 4)[0];
    };
    auto write_V = [&](const ushort4* r, int buf) {
        #pragma unroll
        for (int i = 0; i < 2; ++i) {
            int e8 = veg + i * 4;
            ushort4 lo = r[i * 2], hi = r[i * 2 + 1];
            u16* base = &Vts[buf][e8 * 8 * 64];
            base[0 * 64 + (vk ^ 0)]  = lo.x;
            base[1 * 64 + (vk ^ 8)]  = lo.y;
            base[2 * 64 + (vk ^ 16)] = lo.z;
            base[3 * 64 + (vk ^ 24)] = lo.w;
            base[4 * 64 + (vk ^ 32)] = hi.x;
            base[5 * 64 + (vk ^ 40)] = hi.y;
            base[6 * 64 + (vk ^ 48)] = hi.z;
            base[7 * 64 + (vk ^ 56)] = hi.w;
        }
    };

    {
        ushort4 vr[4];
        issue_K(0, 0);
        load_V(0, vr);
        write_V(vr, 0);
    }
    __syncthreads();

    for (int kt = 0; kt < nt; ++kt) {
        const int k0 = kt * 64;
        const int cur = kt & 1, nxt = cur ^ 1;
        const bool has_next = (kt + 1 < nt);

        ushort4 vr[4];
        if (has_next) {
            issue_K(kt + 1, nxt);
            load_V(kt + 1, vr);
        }

        // S = Q K^T
        f32x4 s[4] = {};
        __builtin_amdgcn_s_setprio(1);
        #pragma unroll
        for (int n = 0; n < 4; ++n) {
            int kr = n * 16 + fr;
            int sw = (fr & 7) << 3;
            bf16x8 kb0 = *reinterpret_cast<const bf16x8*>(&Ks[cur][kr * 64 + ((fq * 8) ^ sw)]);
            bf16x8 kb1 = *reinterpret_cast<const bf16x8*>(&Ks[cur][kr * 64 + ((32 + fq * 8) ^ sw)]);
            s[n] = __builtin_amdgcn_mfma_f32_16x16x32_bf16(qa0, kb0, s[n], 0, 0, 0);
            s[n] = __builtin_amdgcn_mfma_f32_16x16x32_bf16(qa1, kb1, s[n], 0, 0, 0);
        }
        __builtin_amdgcn_s_setprio(0);

        // mask (skipped on interior full tiles) + per-row tile max
        float tmax[4] = {-1e30f, -1e30f, -1e30f, -1e30f};
        const bool fullt = (k0 + 63 <= qrow) && (k0 + 64 <= len);
        if (fullt) {
            #pragma unroll
            for (int n = 0; n < 4; ++n)
                #pragma unroll
                for (int j = 0; j < 4; ++j)
                    tmax[j] = fmaxf(tmax[j], s[n][j]);
        } else {
            #pragma unroll
            for (int n = 0; n < 4; ++n) {
                int kg = k0 + n * 16 + fr;
                bool kv = (kg < len);
                #pragma unroll
                for (int j = 0; j < 4; ++j) {
                    int qg = qrow + fq * 4 + j;
                    float sc = s[n][j];
                    sc = (kv && kg <= qg) ? sc : -1e30f;
                    s[n][j] = sc;
                    tmax[j] = fmaxf(tmax[j], sc);
                }
            }
        }
        #pragma unroll
        for (int j = 0; j < 4; ++j) tmax[j] = red16_max(tmax[j]);

        // defer-max (T13)
        bool need = false;
        #pragma unroll
        for (int j = 0; j < 4; ++j) need |= (tmax[j] > m_s[j] + 8.f);
        if (__any(need)) {
            #pragma unroll
            for (int j = 0; j < 4; ++j) {
                float mn = fmaxf(m_s[j], tmax[j]);
                float f = __expf(m_s[j] - mn);
                m_s[j] = mn; l_s[j] *= f;
                #pragma unroll
                for (int n = 0; n < 4; ++n) o_acc[n][j] *= f;
            }
        }
        #pragma unroll
        for (int n = 0; n < 4; ++n)
            #pragma unroll
            for (int j = 0; j < 4; ++j) {
                float p = __expf(s[n][j] - m_s[j]);
                s[n][j] = p; l_s[j] += p;
            }

        // P -> per-wave LDS (swizzled)
        #pragma unroll
        for (int n = 0; n < 4; ++n)
            #pragma unroll
            for (int j = 0; j < 4; ++j) {
                int prow = fq * 4 + j;
                Ps[wave][prow * 64 + ((n * 16 + fr) ^ ((prow & 7) << 3))] = f2bf(s[n][j]);
            }

        // O += P V
        __builtin_amdgcn_s_setprio(1);
        #pragma unroll
        for (int ks = 0; ks < 2; ++ks) {
            bf16x8 pa = *reinterpret_cast<const bf16x8*>(
                &Ps[wave][fr * 64 + ((ks * 32 + fq * 8) ^ ((fr & 7) << 3))]);
            #pragma unroll
            for (int n = 0; n < 4; ++n) {
                int vr2 = n * 16 + fr;
                bf16x8 vb2 = *reinterpret_cast<const bf16x8*>(
                    &Vts[cur][vr2 * 64 + ((ks * 32 + fq * 8) ^ ((fr & 7) << 3))]);
                o_acc[n] = __builtin_amdgcn_mfma_f32_16x16x32_bf16(pa, vb2, o_acc[n], 0, 0, 0);
            }
        }
        __builtin_amdgcn_s_setprio(0);

        if (has_next) write_V(vr, nxt);
        __syncthreads();
    }

    // epilogue: DPP l-reduce, then O / l
    #pragma unroll
    for (int j = 0; j < 4; ++j) l_s[j] = red16_sum(l_s[j]);
    #pragma unroll
    for (int j = 0; j < 4; ++j) {
        float inv = 1.f / l_s[j];
        int row = qrow + fq * 4 + j;
        #pragma unroll
        for (int n = 0; n < 4; ++n) {
            int col = h * 64 + n * 16 + fr;
            Ob[(size_t)(b * 2048 + row) * 1024 + col] = f2bf(o_acc[n][j] * inv);
        }
    }
}

// ------------------------------ launch -------------------------------------
extern "C" void kernel_launch(void* const* d_in, const int* in_sizes, int n_in,
                              void* d_out, int out_size, void* d_ws, size_t ws_size,
                              hipStream_t stream) {
    const float* xq_f = (const float*)d_in[0];
    const float* xk_f = (const float*)d_in[1];
    const int* kpm = (const int*)d_in[3];
    const float* Wq = (const float*)d_in[4];
    const float* bq = (const float*)d_in[5];
    const float* Wk = (const float*)d_in[6];
    const float* bk = (const float*)d_in[7];
    const float* Wv = (const float*)d_in[8];
    const float* bv = (const float*)d_in[9];
    const float* Wo = (const float*)d_in[10];
    const float* bo = (const float*)d_in[11];

    u16* ws = (u16*)d_ws;
    u16* xq = ws;
    u16* xk = xq + 4194304;
    u16* wq = xk + 4194304;
    u16* wk = wq + 1048576;
    u16* wv = wk + 1048576;
    u16* wo = wv + 1048576;
    u16* qb = wo + 1048576;
    u16* kb2 = qb + 4194304;
    u16* vb2 = kb2 + 4194304;
    u16* ag = vb2 + 4194304;
    int* lens = (int*)(ag + 4194304);

    compute_lens<<<2, 1024, 0, stream>>>(kpm, lens);
    cvt_all<<<12288, 256, 0, stream>>>(xq_f, xk_f, Wq, Wk, Wv, Wo,
                                       xq, xk, wq, wk, wv, wo);

    gemm_qkv<<<dim3(8, 32, 3), 256, 0, stream>>>(xq, xk, wq, wk, wv,
                                                 bq, bk, bv, qb, kb2, vb2);

    attn_fwd<<<dim3(32, 32), 256, 0, stream>>>(qb, kb2, vb2, lens, ag);

    gemm_out<<<dim3(8, 32), 256, 0, stream>>>(ag, wo, bo, (float*)d_out);
}